// Round 2
// baseline (536.261 us; speedup 1.0000x reference)
//
#include <hip/hip_runtime.h>

typedef unsigned short u16;
typedef __attribute__((ext_vector_type(8))) short short8;
typedef __attribute__((ext_vector_type(4))) unsigned short u16x4;
typedef __attribute__((ext_vector_type(4))) float f32x4;

#define DEV __device__ __forceinline__

DEV float bf2f(u16 u) { return __uint_as_float(((unsigned int)u) << 16); }
DEV u16 f2bf(float f) {
  unsigned int u = __float_as_uint(f);
  u += 0x7FFF + ((u >> 16) & 1);
  return (u16)(u >> 16);
}

DEV float redmax16(float v) {
  v = fmaxf(v, __shfl_xor(v, 1));
  v = fmaxf(v, __shfl_xor(v, 2));
  v = fmaxf(v, __shfl_xor(v, 4));
  v = fmaxf(v, __shfl_xor(v, 8));
  return v;
}
DEV float redsum16(float v) {
  v += __shfl_xor(v, 1);
  v += __shfl_xor(v, 2);
  v += __shfl_xor(v, 4);
  v += __shfl_xor(v, 8);
  return v;
}

// ---------------- transpose + cast f32 -> bf16, 32x32 tiles ----------------
// in: f32 [R][C], out: bf16 [C][R]
__global__ __launch_bounds__(256) void transpose_f32_bf16(const float* __restrict__ in,
                                                          u16* __restrict__ out,
                                                          int R, int C) {
  __shared__ u16 tile[32][33];
  int tx = threadIdx.x & 31, ty = threadIdx.x >> 5;  // 32 x 8
  int r0 = blockIdx.y * 32, c0 = blockIdx.x * 32;
#pragma unroll
  for (int i = 0; i < 32; i += 8)
    tile[ty + i][tx] = f2bf(in[(size_t)(r0 + ty + i) * C + c0 + tx]);
  __syncthreads();
#pragma unroll
  for (int i = 0; i < 32; i += 8)
    out[(size_t)(c0 + ty + i) * R + r0 + tx] = tile[tx][ty + i];
}

// ---------------- RMSNorm: 8192 rows x 1024, f32 in -> bf16 out ----------------
__global__ __launch_bounds__(256) void rmsnorm_kernel(const float* __restrict__ x,
                                                      const float* __restrict__ w,
                                                      u16* __restrict__ xn) {
  int row = blockIdx.x, t = threadIdx.x;
  const float4* xr = reinterpret_cast<const float4*>(x + (size_t)row * 1024);
  float4 v = xr[t];
  float ss = v.x * v.x + v.y * v.y + v.z * v.z + v.w * v.w;
#pragma unroll
  for (int d = 1; d < 64; d <<= 1) ss += __shfl_xor(ss, d);
  __shared__ float red[4];
  if ((t & 63) == 0) red[t >> 6] = ss;
  __syncthreads();
  float tot = red[0] + red[1] + red[2] + red[3];
  float inv = rsqrtf(tot * (1.0f / 1024.0f) + 1e-6f);
  float4 wv = reinterpret_cast<const float4*>(w)[t];
  u16x4 o;
  o[0] = f2bf(v.x * inv * wv.x);
  o[1] = f2bf(v.y * inv * wv.y);
  o[2] = f2bf(v.z * inv * wv.z);
  o[3] = f2bf(v.w * inv * wv.w);
  *reinterpret_cast<u16x4*>(xn + (size_t)row * 1024 + t * 4) = o;
}

// ---------------- RoPE in-place on q,k halves of qkv (bf16), f32 sin/cos ------
__global__ __launch_bounds__(256) void rope_kernel(u16* __restrict__ qkv,
                                                   const float* __restrict__ sp,
                                                   const float* __restrict__ cp) {
  size_t i = (size_t)blockIdx.x * 256 + threadIdx.x;  // pair index, 8192*1024 total
  int row = (int)(i >> 10);
  int e2 = (int)(i & 1023);
  int pos = row & 4095;
  int elem = e2 * 2;  // within [q(1024) | k(1024)]
  int d = elem & 63;
  size_t off = (size_t)row * 3072 + elem;
  float xe = bf2f(qkv[off]), xo = bf2f(qkv[off + 1]);
  float s0 = sp[pos * 64 + d], s1 = sp[pos * 64 + d + 1];
  float c0 = cp[pos * 64 + d], c1 = cp[pos * 64 + d + 1];
  qkv[off] = f2bf(xe * c0 - xo * s0);
  qkv[off + 1] = f2bf(xo * c1 + xe * s1);
}

// ---------------- GEMM: C[M][N] = A[M][K] @ BT[N][K]^T + bias ----------------
// mode 0: bf16 out; mode 1: bf16 out + exact GELU; mode 2: f32 out
// grid (N/128, M/128), block 256 (4 waves, 2x2 of 64x64)
__global__ __launch_bounds__(256) void gemm_bt(const u16* __restrict__ A,
                                               const u16* __restrict__ BT,
                                               const float* __restrict__ bias,
                                               void* __restrict__ Cout,
                                               int K, int ldc, int mode) {
  __shared__ u16 Al[128 * 32];
  __shared__ u16 Bl[128 * 32];
  int t = threadIdx.x;
  int w = t >> 6, l = t & 63, c = l & 15, g = l >> 4;
  int wr = w >> 1, wc = w & 1;
  size_t m0 = (size_t)blockIdx.y * 128, n0 = (size_t)blockIdx.x * 128;

  f32x4 zero4 = {0.f, 0.f, 0.f, 0.f};
  f32x4 acc[4][4];
#pragma unroll
  for (int a = 0; a < 4; ++a)
#pragma unroll
    for (int b2 = 0; b2 < 4; ++b2) acc[a][b2] = zero4;

  const u16* Abase = A + m0 * K;
  const u16* Bbase = BT + n0 * K;

  for (int kt = 0; kt < K; kt += 32) {
    if (kt) __syncthreads();
#pragma unroll
    for (int j = 0; j < 2; ++j) {
      int idx = j * 256 + t;
      int row = idx >> 2, seg = idx & 3;
      const u16* ga = Abase + (size_t)row * K + kt + seg * 8;
      const u16* gb = Bbase + (size_t)row * K + kt + seg * 8;
      __builtin_amdgcn_global_load_lds(
          (const __attribute__((address_space(1))) unsigned int*)ga,
          (__attribute__((address_space(3))) unsigned int*)((char*)Al + idx * 16),
          16, 0, 0);
      __builtin_amdgcn_global_load_lds(
          (const __attribute__((address_space(1))) unsigned int*)gb,
          (__attribute__((address_space(3))) unsigned int*)((char*)Bl + idx * 16),
          16, 0, 0);
    }
    __syncthreads();
    short8 bv[4];
#pragma unroll
    for (int nj = 0; nj < 4; ++nj)
      bv[nj] = *reinterpret_cast<const short8*>(Bl + ((wc * 64 + 16 * nj + c) * 32 + 8 * g));
#pragma unroll
    for (int mi = 0; mi < 4; ++mi) {
      short8 av = *reinterpret_cast<const short8*>(Al + ((wr * 64 + 16 * mi + c) * 32 + 8 * g));
#pragma unroll
      for (int nj = 0; nj < 4; ++nj)
        acc[mi][nj] = __builtin_amdgcn_mfma_f32_16x16x32_bf16(av, bv[nj], acc[mi][nj], 0, 0, 0);
    }
  }

#pragma unroll
  for (int nj = 0; nj < 4; ++nj) {
    int col = (int)n0 + wc * 64 + 16 * nj + c;
    float bvv = bias[col];
#pragma unroll
    for (int mi = 0; mi < 4; ++mi) {
      size_t rbase = m0 + wr * 64 + 16 * mi + 4 * g;
#pragma unroll
      for (int r = 0; r < 4; ++r) {
        float f = acc[mi][nj][r] + bvv;
        if (mode == 1) f = 0.5f * f * (1.0f + erff(f * 0.70710678f));
        size_t oidx = (rbase + r) * (size_t)ldc + col;
        if (mode == 2)
          ((float*)Cout)[oidx] = f;
        else
          ((u16*)Cout)[oidx] = f2bf(f);
      }
    }
  }
}

// ---------------- sliding-window causal attention ----------------
// 1 wave per 64-query tile. grid = B*NH*(S/64) = 2048, block = 64.
// qkv rows: [q(16x64) | k(16x64) | v(16x64)] bf16, row stride 3072.
// out -> comb cols [0,1024), bf16
__global__ __launch_bounds__(64) void attn_kernel(const u16* __restrict__ qkv,
                                                  u16* __restrict__ comb) {
  int wg = blockIdx.x;
  int qt = wg & 63, h = (wg >> 6) & 15, b = wg >> 10;
  int l = threadIdx.x, c = l & 15, g = l >> 4;
  int q0 = qt * 64;
  const u16* qb = qkv + (size_t)b * 4096 * 3072 + h * 64;
  const u16* kb = qb + 1024;
  const u16* vb = qb + 2048;
  __shared__ u16 Pl[64 * 72];

  short8 qf[4][2];
#pragma unroll
  for (int mi = 0; mi < 4; ++mi)
#pragma unroll
    for (int kk = 0; kk < 2; ++kk)
      qf[mi][kk] = *reinterpret_cast<const short8*>(
          qb + (size_t)(q0 + 16 * mi + c) * 3072 + 32 * kk + 8 * g);

  f32x4 zero4 = {0.f, 0.f, 0.f, 0.f};
  f32x4 o[4][4];
  float mr[4][4], lr[4][4];
#pragma unroll
  for (int a = 0; a < 4; ++a)
#pragma unroll
    for (int d2 = 0; d2 < 4; ++d2) {
      o[a][d2] = zero4;
      mr[a][d2] = -1e30f;
      lr[a][d2] = 0.f;
    }

  int t_lo = qt >= 8 ? qt - 8 : 0;
  for (int tt = t_lo; tt <= qt; ++tt) {
    int kt0 = tt * 64;
    f32x4 s[4][4];
#pragma unroll
    for (int a = 0; a < 4; ++a)
#pragma unroll
      for (int d2 = 0; d2 < 4; ++d2) s[a][d2] = zero4;

#pragma unroll
    for (int kk = 0; kk < 2; ++kk) {
      short8 kf[4];
#pragma unroll
      for (int nj = 0; nj < 4; ++nj)
        kf[nj] = *reinterpret_cast<const short8*>(
            kb + (size_t)(kt0 + 16 * nj + c) * 3072 + 32 * kk + 8 * g);
#pragma unroll
      for (int mi = 0; mi < 4; ++mi)
#pragma unroll
        for (int nj = 0; nj < 4; ++nj)
          s[mi][nj] = __builtin_amdgcn_mfma_f32_16x16x32_bf16(qf[mi][kk], kf[nj], s[mi][nj], 0, 0, 0);
    }

    bool mc = (tt == qt), mw = (tt == qt - 8);
#pragma unroll
    for (int mi = 0; mi < 4; ++mi)
#pragma unroll
      for (int nj = 0; nj < 4; ++nj)
#pragma unroll
        for (int r = 0; r < 4; ++r) {
          int qg = q0 + 16 * mi + 4 * g + r;
          int kg = kt0 + 16 * nj + c;
          float v = s[mi][nj][r] * 0.125f;
          if ((mc && kg > qg) || (mw && qg - kg >= 512)) v = -1e30f;
          s[mi][nj][r] = v;
        }

    float alpha[4][4];
#pragma unroll
    for (int mi = 0; mi < 4; ++mi)
#pragma unroll
      for (int r = 0; r < 4; ++r) {
        float tm = fmaxf(fmaxf(s[mi][0][r], s[mi][1][r]), fmaxf(s[mi][2][r], s[mi][3][r]));
        tm = redmax16(tm);
        float mn = fmaxf(mr[mi][r], tm);
        alpha[mi][r] = __expf(mr[mi][r] - mn);
        mr[mi][r] = mn;
        float rs = 0.f;
        u16x4 pk;
#pragma unroll
        for (int nj = 0; nj < 4; ++nj) {
          float p = __expf(s[mi][nj][r] - mn);
          rs += p;
          pk[nj] = f2bf(p);
        }
        rs = redsum16(rs);
        lr[mi][r] = lr[mi][r] * alpha[mi][r] + rs;
        // P stored with k-permutation pi(k)=4*(k&15)+(k>>4): packed b64 write
        *reinterpret_cast<u16x4*>(&Pl[(16 * mi + 4 * g + r) * 72 + 4 * c]) = pk;
      }
#pragma unroll
    for (int mi = 0; mi < 4; ++mi)
#pragma unroll
      for (int dj = 0; dj < 4; ++dj)
#pragma unroll
        for (int r = 0; r < 4; ++r) o[mi][dj][r] *= alpha[mi][r];

    // PV: A-frag from Pl (pi-space), B-frag = V scalars loaded in matching pi-space
#pragma unroll
    for (int kk = 0; kk < 2; ++kk) {
      short8 pa[4];
#pragma unroll
      for (int mi = 0; mi < 4; ++mi)
        pa[mi] = *reinterpret_cast<const short8*>(&Pl[(16 * mi + c) * 72 + 32 * kk + 8 * g]);
      short8 bv[4];
#pragma unroll
      for (int dj = 0; dj < 4; ++dj)
#pragma unroll
        for (int i = 0; i < 8; ++i) {
          int jp = 32 * kk + 8 * g + i;
          int key = 16 * (jp & 3) + (jp >> 2);  // inverse of pi
          bv[dj][i] = (short)vb[(size_t)(kt0 + key) * 3072 + 16 * dj + c];
        }
#pragma unroll
      for (int mi = 0; mi < 4; ++mi)
#pragma unroll
        for (int dj = 0; dj < 4; ++dj)
          o[mi][dj] = __builtin_amdgcn_mfma_f32_16x16x32_bf16(pa[mi], bv[dj], o[mi][dj], 0, 0, 0);
    }
  }

  u16* ob = comb + (size_t)(b * 4096 + q0) * 5120 + h * 64;
#pragma unroll
  for (int mi = 0; mi < 4; ++mi)
#pragma unroll
    for (int dj = 0; dj < 4; ++dj)
#pragma unroll
      for (int r = 0; r < 4; ++r)
        ob[(size_t)(16 * mi + 4 * g + r) * 5120 + 16 * dj + c] = f2bf(o[mi][dj][r] / lr[mi][r]);
}

// ---------------- launch ----------------
extern "C" void kernel_launch(void* const* d_in, const int* in_sizes, int n_in,
                              void* d_out, int out_size, void* d_ws, size_t ws_size,
                              hipStream_t stream) {
  const float* x = (const float*)d_in[0];
  const float* sinp = (const float*)d_in[1];
  const float* cosp = (const float*)d_in[2];
  const float* norm_w = (const float*)d_in[3];
  const float* w_qkv = (const float*)d_in[4];
  const float* b_qkv = (const float*)d_in[5];
  const float* w_in = (const float*)d_in[6];
  const float* b_in = (const float*)d_in[7];
  const float* w_out = (const float*)d_in[8];
  const float* b_out = (const float*)d_in[9];
  float* out = (float*)d_out;

  char* ws = (char*)d_ws;
  u16* xn = (u16*)(ws);                        // 8192*1024*2      = 16,777,216
  u16* qkv = (u16*)(ws + 16777216);            // 8192*3072*2      = 50,331,648
  u16* comb = (u16*)(ws + 67108864);           // 8192*5120*2      = 83,886,080
  u16* wqkvT = (u16*)(ws + 150994944);         // 3072*1024*2      = 6,291,456
  u16* winT = (u16*)(ws + 157286400);          // 4096*1024*2      = 8,388,608
  u16* woutT = (u16*)(ws + 165675008);         // 1024*5120*2      = 10,485,760

  transpose_f32_bf16<<<dim3(3072 / 32, 1024 / 32), 256, 0, stream>>>(w_qkv, wqkvT, 1024, 3072);
  transpose_f32_bf16<<<dim3(4096 / 32, 1024 / 32), 256, 0, stream>>>(w_in, winT, 1024, 4096);
  transpose_f32_bf16<<<dim3(1024 / 32, 5120 / 32), 256, 0, stream>>>(w_out, woutT, 5120, 1024);

  rmsnorm_kernel<<<8192, 256, 0, stream>>>(x, norm_w, xn);

  // qkv = xn @ w_qkv + b_qkv   (bf16 out)
  gemm_bt<<<dim3(3072 / 128, 8192 / 128), 256, 0, stream>>>(xn, wqkvT, b_qkv, qkv, 1024, 3072, 0);

  rope_kernel<<<32768, 256, 0, stream>>>(qkv, sinp, cosp);

  attn_kernel<<<2048, 64, 0, stream>>>(qkv, comb);

  // ff = gelu(xn @ w_in + b_in) -> comb cols [1024, 5120)  (bf16 out)
  gemm_bt<<<dim3(4096 / 128, 8192 / 128), 256, 0, stream>>>(xn, winT, b_in, comb + 1024, 1024, 5120, 1);

  // out = comb @ w_out + b_out  (f32 out)
  gemm_bt<<<dim3(1024 / 128, 8192 / 128), 256, 0, stream>>>(comb, woutT, b_out, out, 5120, 1024, 2);
}